// Round 1
// baseline (38917.154 us; speedup 1.0000x reference)
//
#include <hip/hip_runtime.h>
#include <hip/hip_cooperative_groups.h>

namespace cg = cooperative_groups;

#define B_ 64
#define T_ 512
#define V_ 512
#define H_ 1024

typedef short bf16x8 __attribute__((ext_vector_type(8)));
typedef float f32x4 __attribute__((ext_vector_type(4)));

// ---- workspace layout (ushort element offsets) ----
#define EO_PHR 0
#define EO_PHZ (EO_PHR + H_*H_)
#define EO_PHH (EO_PHZ + H_*H_)
#define EO_PXR (EO_PHH + H_*H_)
#define EO_PXZ (EO_PXR + V_*H_)
#define EO_PXH (EO_PXZ + V_*H_)
#define EO_PHO (EO_PXH + V_*H_)
#define EO_HBF (EO_PHO + H_*V_)          // 2 buffers of [64][1024] bf16
#define EO_RHBF (EO_HBF + 2*B_*H_)       // [64][1024] bf16
#define EO_USEND (EO_RHBF + B_*H_)
// fp32 rings (xr, xz, xh; each [2][64][1024]) start at byte 2*EO_USEND

__device__ __forceinline__ unsigned short f2bf(float x) {
  unsigned u = __builtin_bit_cast(unsigned, x);
  u = u + 0x7fffu + ((u >> 16) & 1u);   // round-to-nearest-even
  return (unsigned short)(u >> 16);
}
__device__ __forceinline__ float bf2f(unsigned short b) {
  return __builtin_bit_cast(float, (unsigned)b << 16);
}

// ---------------- weight pre-pack: fp32 [K][N] -> bf16 MFMA B-fragment layout
// packed[((nt*KT + kt)*64 + lane)*8 + j] = W[kt*32 + (lane>>4)*8 + j][nt*16 + (lane&15)]
__global__ void pack_weights(const float* __restrict__ w_hr, const float* __restrict__ w_hz,
                             const float* __restrict__ w_hh, const float* __restrict__ w_xr,
                             const float* __restrict__ w_xz, const float* __restrict__ w_xh,
                             const float* __restrict__ w_ho, unsigned short* __restrict__ ws) {
  int tid = blockIdx.x * blockDim.x + threadIdx.x;
  const int NH = 64*32*64, NX = 64*16*64, NO = 32*32*64;
  if (tid < 3*NH) {                       // w_hr / w_hz / w_hh : [1024][1024]
    int m = tid / NH, idx = tid % NH;
    const float* src = (m==0) ? w_hr : (m==1) ? w_hz : w_hh;
    unsigned short* dst = ws + ((m==0) ? EO_PHR : (m==1) ? EO_PHZ : EO_PHH);
    int l = idx & 63, kt = (idx >> 6) & 31, nt = idx >> 11;
    int n = nt*16 + (l & 15), k0 = kt*32 + (l >> 4)*8;
    #pragma unroll
    for (int j = 0; j < 8; ++j) dst[idx*8 + j] = f2bf(src[(size_t)(k0+j)*H_ + n]);
    return;
  }
  tid -= 3*NH;
  if (tid < 3*NX) {                       // w_xr / w_xz / w_xh : [512][1024]
    int m = tid / NX, idx = tid % NX;
    const float* src = (m==0) ? w_xr : (m==1) ? w_xz : w_xh;
    unsigned short* dst = ws + ((m==0) ? EO_PXR : (m==1) ? EO_PXZ : EO_PXH);
    int l = idx & 63, kt = (idx >> 6) & 15, nt = idx >> 10;
    int n = nt*16 + (l & 15), k0 = kt*32 + (l >> 4)*8;
    #pragma unroll
    for (int j = 0; j < 8; ++j) dst[idx*8 + j] = f2bf(src[(size_t)(k0+j)*H_ + n]);
    return;
  }
  tid -= 3*NX;
  if (tid < NO) {                         // w_ho : [1024][512]
    int idx = tid;
    unsigned short* dst = ws + EO_PHO;
    int l = idx & 63, kt = (idx >> 6) & 31, nt = idx >> 11;
    int n = nt*16 + (l & 15), k0 = kt*32 + (l >> 4)*8;
    #pragma unroll
    for (int j = 0; j < 8; ++j) dst[idx*8 + j] = f2bf(w_ho[(size_t)(k0+j)*V_ + n]);
  }
}

// GEMM over bf16 state A [64][1024] x packed B (KT=32) -> one 16x16 D tile (mt,nt)
__device__ __forceinline__ f32x4 hgemm(const unsigned short* __restrict__ A,
                                       const unsigned short* __restrict__ Pk,
                                       int nt, int mt, int lane) {
  f32x4 acc = {0.f, 0.f, 0.f, 0.f};
  const unsigned short* ap = A + (mt*16 + (lane & 15))*H_ + ((lane >> 4)*8);
  const unsigned short* bp = Pk + ((size_t)nt*32*64 + lane)*8;
  #pragma unroll 8
  for (int kt = 0; kt < 32; ++kt) {
    bf16x8 a = *(const bf16x8*)(const void*)(ap + kt*32);
    bf16x8 b = *(const bf16x8*)(const void*)(bp + (size_t)kt*512);
    acc = __builtin_amdgcn_mfma_f32_16x16x32_bf16(a, b, acc, 0, 0, 0);
  }
  return acc;
}

// GEMM over fp32 X slice (t fixed, K=512, convert to bf16 on the fly) x packed B (KT=16)
__device__ __forceinline__ f32x4 xgemm(const float* __restrict__ X, int t,
                                       const unsigned short* __restrict__ Pk,
                                       int nt, int mt, int lane) {
  f32x4 acc = {0.f, 0.f, 0.f, 0.f};
  const float* rp = X + (size_t)(mt*16 + (lane & 15))*(T_*V_) + (size_t)t*V_ + ((lane >> 4)*8);
  const unsigned short* bp = Pk + ((size_t)nt*16*64 + lane)*8;
  #pragma unroll 4
  for (int kt = 0; kt < 16; ++kt) {
    float4 x0 = *(const float4*)(rp + kt*32);
    float4 x1 = *(const float4*)(rp + kt*32 + 4);
    bf16x8 a;
    a[0] = (short)f2bf(x0.x); a[1] = (short)f2bf(x0.y);
    a[2] = (short)f2bf(x0.z); a[3] = (short)f2bf(x0.w);
    a[4] = (short)f2bf(x1.x); a[5] = (short)f2bf(x1.y);
    a[6] = (short)f2bf(x1.z); a[7] = (short)f2bf(x1.w);
    bf16x8 b = *(const bf16x8*)(const void*)(bp + (size_t)kt*512);
    acc = __builtin_amdgcn_mfma_f32_16x16x32_bf16(a, b, acc, 0, 0, 0);
  }
  return acc;
}

__global__ void __launch_bounds__(256, 1) gru_main(
    const float* __restrict__ X, const float* __restrict__ state,
    const float* __restrict__ b_r, const float* __restrict__ b_z,
    const float* __restrict__ b_h, const float* __restrict__ b_o,
    float* __restrict__ out, unsigned short* ws) {
  cg::grid_group grid = cg::this_grid();
  const int blk  = blockIdx.x;
  const int wave = threadIdx.x >> 6;
  const int lane = threadIdx.x & 63;
  const int dcol = lane & 15;
  const int drow = (lane >> 4) * 4;

  const unsigned short* Phr = ws + EO_PHR;
  const unsigned short* Phz = ws + EO_PHZ;
  const unsigned short* Phh = ws + EO_PHH;
  const unsigned short* Pxr = ws + EO_PXR;
  const unsigned short* Pxz = ws + EO_PXZ;
  const unsigned short* Pxh = ws + EO_PXH;
  const unsigned short* Pho = ws + EO_PHO;
  unsigned short* HbfBase = ws + EO_HBF;
  unsigned short* RHbf    = ws + EO_RHBF;
  float* fbase = (float*)(ws + EO_USEND);
  float* xrr = fbase;                 // [2][B_*H_]
  float* xzr = fbase + 2*B_*H_;
  float* xhr = fbase + 4*B_*H_;

  f32x4 hreg  = {0.f, 0.f, 0.f, 0.f};   // fp32 master H (blocks 0-63)
  f32x4 zfrag = {0.f, 0.f, 0.f, 0.f};

  // ---------------- prologue: init H, compute xr_0 / xz_0 / xh_0 ----------------
  if (blk < 64) {
    int nt = blk, mt = wave;
    #pragma unroll
    for (int q = 0; q < 4; ++q) {
      int b = mt*16 + drow + q, n = nt*16 + dcol;
      float h0 = state[b*H_ + n];
      hreg[q] = h0;
      HbfBase[b*H_ + n] = f2bf(h0);
    }
  } else if (blk < 128) {
    int nt = blk - 64, mt = wave;
    f32x4 acc = xgemm(X, 0, Pxr, nt, mt, lane);
    int n = nt*16 + dcol; float bias = b_r[n];
    #pragma unroll
    for (int q = 0; q < 4; ++q) xrr[(mt*16 + drow + q)*H_ + n] = acc[q] + bias;
  } else if (blk < 192) {
    int nt = blk - 128, mt = wave;
    f32x4 acc = xgemm(X, 0, Pxz, nt, mt, lane);
    int n = nt*16 + dcol; float bias = b_z[n];
    #pragma unroll
    for (int q = 0; q < 4; ++q) xzr[(mt*16 + drow + q)*H_ + n] = acc[q] + bias;
  } else {
    int nt = blk - 192, mt = wave;
    f32x4 acc = xgemm(X, 0, Pxh, nt, mt, lane);
    int n = nt*16 + dcol; float bias = b_h[n];
    #pragma unroll
    for (int q = 0; q < 4; ++q) xhr[(mt*16 + drow + q)*H_ + n] = acc[q] + bias;
  }
  grid.sync();

  // ---------------- time loop ----------------
  for (int i = 0; i < T_; ++i) {
    const unsigned short* Hcur = HbfBase + (i & 1) * (B_*H_);
    unsigned short* Hnxt = HbfBase + ((i + 1) & 1) * (B_*H_);

    // ---- phase A: z, r->r*H, o_{i-1}, xh_{i+1} ----
    if (blk < 64) {
      int nt = blk, mt = wave;
      f32x4 acc = hgemm(Hcur, Phz, nt, mt, lane);
      const float* xz = xzr + (i & 1) * (B_*H_);
      int n = nt*16 + dcol;
      #pragma unroll
      for (int q = 0; q < 4; ++q) {
        int b = mt*16 + drow + q;
        float a = acc[q] + xz[b*H_ + n];
        zfrag[q] = 1.f / (1.f + __expf(-a));
      }
    } else if (blk < 128) {
      int nt = blk - 64, mt = wave;
      f32x4 acc = hgemm(Hcur, Phr, nt, mt, lane);
      const float* xr = xrr + (i & 1) * (B_*H_);
      int n = nt*16 + dcol;
      #pragma unroll
      for (int q = 0; q < 4; ++q) {
        int b = mt*16 + drow + q;
        float r = 1.f / (1.f + __expf(-(acc[q] + xr[b*H_ + n])));
        float hv = bf2f(Hcur[b*H_ + n]);
        RHbf[b*H_ + n] = f2bf(r * hv);
      }
    } else if (blk < 160) {
      if (i > 0) {
        int nt = blk - 128, mt = wave;
        f32x4 acc = hgemm(Hcur, Pho, nt, mt, lane);
        int n = nt*16 + dcol; float bias = b_o[n];
        #pragma unroll
        for (int q = 0; q < 4; ++q) {
          int b = mt*16 + drow + q;
          out[((size_t)(i-1)*B_ + b)*V_ + n] = acc[q] + bias;
        }
      }
    } else if (blk >= 192) {
      if (i + 1 < T_) {
        int nt = blk - 192, mt = wave;
        f32x4 acc = xgemm(X, i + 1, Pxh, nt, mt, lane);
        float* xh = xhr + ((i + 1) & 1) * (B_*H_);
        int n = nt*16 + dcol; float bias = b_h[n];
        #pragma unroll
        for (int q = 0; q < 4; ++q) xh[(mt*16 + drow + q)*H_ + n] = acc[q] + bias;
      }
    }
    grid.sync();

    // ---- phase B: h_bar + H update, xr_{i+1}, xz_{i+1} ----
    if (blk < 64) {
      int nt = blk, mt = wave;
      f32x4 acc = hgemm(RHbf, Phh, nt, mt, lane);
      const float* xh = xhr + (i & 1) * (B_*H_);
      int n = nt*16 + dcol;
      #pragma unroll
      for (int q = 0; q < 4; ++q) {
        int b = mt*16 + drow + q;
        float hb = tanhf(acc[q] + xh[b*H_ + n]);
        float z = zfrag[q];
        float hn = hreg[q] * z + hb * (1.f - z);
        hreg[q] = hn;
        Hnxt[b*H_ + n] = f2bf(hn);
      }
    } else if (blk < 128) {
      if (i + 1 < T_) {
        int nt = blk - 64, mt = wave;
        f32x4 acc = xgemm(X, i + 1, Pxr, nt, mt, lane);
        float* xr = xrr + ((i + 1) & 1) * (B_*H_);
        int n = nt*16 + dcol; float bias = b_r[n];
        #pragma unroll
        for (int q = 0; q < 4; ++q) xr[(mt*16 + drow + q)*H_ + n] = acc[q] + bias;
      }
    } else if (blk < 192) {
      if (i + 1 < T_) {
        int nt = blk - 128, mt = wave;
        f32x4 acc = xgemm(X, i + 1, Pxz, nt, mt, lane);
        float* xz = xzr + ((i + 1) & 1) * (B_*H_);
        int n = nt*16 + dcol; float bias = b_z[n];
        #pragma unroll
        for (int q = 0; q < 4; ++q) xz[(mt*16 + drow + q)*H_ + n] = acc[q] + bias;
      }
    }
    grid.sync();
  }

  // ---------------- epilogue: o_{T-1} and H_final ----------------
  if (blk < 64) {
    int nt = blk, mt = wave;
    int n = nt*16 + dcol;
    #pragma unroll
    for (int q = 0; q < 4; ++q) {
      int b = mt*16 + drow + q;
      out[(size_t)T_*B_*V_ + b*H_ + n] = hreg[q];
    }
  } else if (blk >= 128 && blk < 160) {
    int nt = blk - 128, mt = wave;
    const unsigned short* Hcur = HbfBase + (T_ & 1) * (B_*H_);
    f32x4 acc = hgemm(Hcur, Pho, nt, mt, lane);
    int n = nt*16 + dcol; float bias = b_o[n];
    #pragma unroll
    for (int q = 0; q < 4; ++q) {
      int b = mt*16 + drow + q;
      out[((size_t)(T_-1)*B_ + b)*V_ + n] = acc[q] + bias;
    }
  }
}

extern "C" void kernel_launch(void* const* d_in, const int* in_sizes, int n_in,
                              void* d_out, int out_size, void* d_ws, size_t ws_size,
                              hipStream_t stream) {
  const float* X     = (const float*)d_in[0];
  const float* state = (const float*)d_in[1];
  const float* w_xr  = (const float*)d_in[2];
  const float* w_hr  = (const float*)d_in[3];
  const float* b_r   = (const float*)d_in[4];
  const float* w_xz  = (const float*)d_in[5];
  const float* w_hz  = (const float*)d_in[6];
  const float* b_z   = (const float*)d_in[7];
  const float* w_xh  = (const float*)d_in[8];
  const float* w_hh  = (const float*)d_in[9];
  const float* b_h   = (const float*)d_in[10];
  const float* w_ho  = (const float*)d_in[11];
  const float* b_o   = (const float*)d_in[12];
  float* outp = (float*)d_out;
  unsigned short* wsp = (unsigned short*)d_ws;

  // one-time (per call) weight conversion + fragment packing
  hipLaunchKernelGGL(pack_weights, dim3(2560), dim3(256), 0, stream,
                     w_hr, w_hz, w_hh, w_xr, w_xz, w_xh, w_ho, wsp);

  void* params[8] = { (void*)&X, (void*)&state, (void*)&b_r, (void*)&b_z,
                      (void*)&b_h, (void*)&b_o, (void*)&outp, (void*)&wsp };
  hipLaunchCooperativeKernel((void*)gru_main, dim3(256), dim3(256), params, 0, stream);
}